// Round 1
// 127.524 us; speedup vs baseline: 1.0003x; 1.0003x over previous
//
#include <hip/hip_runtime.h>
#include <stdint.h>

// LinearInterpolation: out[b, j, c] = lerp(v[b,seg[j],c], v[b,seg[j]+1,c], t[j])
// BATCH=262144, NK=13, M=48, C=2.
//
// Roofline: 100.7 MB write + 27.3 MB read -> ~20 us at ~6.5 TB/s.
// dur_us also contains the harness's 384 MiB poison fill (~60 us, fixed).
//
// R1 change vs previous best (127.6 us):
//  - compile-time specialization <NK=13,M=48>: kills runtime idiv chains
//    (off/half emitted v_rcp sequences), enables full unroll of the 6-store loop
//  - async global->LDS staging via __builtin_amdgcn_global_load_lds width=16,
//    issued FIRST so DMA overlaps seg/t setup; removes VGPR round-trip
//  - packed int2/float2 seg/t, fmaf epilogue
// Generic fallback kernel kept for any other shape.

#define BPB 64  // batches per block

typedef const __attribute__((address_space(1))) unsigned int* gas_t;
typedef __attribute__((address_space(3))) unsigned int* las_t;

static __device__ __forceinline__ void gload_lds16(const void* g, void* l) {
  // wave-uniform LDS base + lane*16; our per-lane addrs are exactly base+lane*16
  __builtin_amdgcn_global_load_lds((gas_t)g, (las_t)l, 16, 0, 0);
}

// ---------------- fast path: shapes baked in ----------------
template <int NK, int M>
__global__ __launch_bounds__(256) void lerp_fast(
    const int* __restrict__ index, const float* __restrict__ value,
    float4* __restrict__ out4) {
  constexpr int HALF = M / 2;              // float4s per batch (24)
  constexpr int ROW  = NK * 2;             // floats per batch (26)
  constexpr int NF4  = (BPB * ROW) / 4;    // 416 staged float4s per block
  constexpr int ITER = (BPB * HALF) / 256; // 6 full store rounds

  __shared__ float4 s_val4[NF4];
  __shared__ int2   s_seg[HALF];
  __shared__ float2 s_t[HALF];

  const int tid = threadIdx.x;
  const int b0  = blockIdx.x * BPB;

  // 1) issue async staging first: 416 float4 in 2 rounds (round 2: 160 lanes)
  {
    const float4* src4 = (const float4*)(value + (size_t)b0 * ROW);
    gload_lds16(src4 + tid, s_val4 + tid);
    const int i = tid + 256;
    if (i < NF4) gload_lds16(src4 + i, s_val4 + i);
  }

  // 2) seg/t for output pair (j0=2*tid, j0+1); overlaps the DMA above.
  //    Knot values read straight from global (52 B, L1-broadcast).
  if (tid < HALF) {
    int kn[NK];
#pragma unroll
    for (int k = 0; k < NK; ++k) kn[k] = index[k];
    const int p0 = kn[0] + 2 * tid + 1;
    const int p1 = p0 + 1;
    int c0 = 0, c1 = 0;
#pragma unroll
    for (int k = 0; k < NK; ++k) {
      c0 += (kn[k] < p0) ? 1 : 0;
      c1 += (kn[k] < p1) ? 1 : 0;
    }
    const int sa = c0 - 1, sb = c1 - 1;
    s_seg[tid] = make_int2(sa, sb);
    s_t[tid] = make_float2(
        (float)(p0 - kn[sa]) / (float)(kn[sa + 1] - kn[sa]),
        (float)(p1 - kn[sb]) / (float)(kn[sb + 1] - kn[sb]));
  }
  __syncthreads();  // drains vmcnt (DMA) + lgkmcnt

  // 3) fully-unrolled compute + contiguous float4 stores
  const float* s_val = (const float*)s_val4;
  float4* __restrict__ dst = out4 + (size_t)b0 * HALF;
#pragma unroll
  for (int k = 0; k < ITER; ++k) {
    const int off = tid + 256 * k;
    const int bl = off / HALF;  // compile-time divisor -> magic mul
    const int jp = off - bl * HALF;
    const int2   sg = s_seg[jp];
    const float2 tt = s_t[jp];
    const float* vb = s_val + bl * ROW;
    const float2 a0 = *(const float2*)(vb + 2 * sg.x);
    const float2 e0 = *(const float2*)(vb + 2 * sg.x + 2);
    const float2 a1 = *(const float2*)(vb + 2 * sg.y);
    const float2 e1 = *(const float2*)(vb + 2 * sg.y + 2);
    float4 o;
    o.x = fmaf(e0.x - a0.x, tt.x, a0.x);
    o.y = fmaf(e0.y - a0.y, tt.x, a0.y);
    o.z = fmaf(e1.x - a1.x, tt.y, a1.x);
    o.w = fmaf(e1.y - a1.y, tt.y, a1.y);
    dst[off] = o;
  }
  if constexpr ((BPB * HALF) % 256 != 0) {  // never for M=48; generality guard
    const int off = tid + 256 * ITER;
    if (off < BPB * HALF) {
      const int bl = off / HALF;
      const int jp = off - bl * HALF;
      const int2   sg = s_seg[jp];
      const float2 tt = s_t[jp];
      const float* vb = s_val + bl * ROW;
      const float2 a0 = *(const float2*)(vb + 2 * sg.x);
      const float2 e0 = *(const float2*)(vb + 2 * sg.x + 2);
      const float2 a1 = *(const float2*)(vb + 2 * sg.y);
      const float2 e1 = *(const float2*)(vb + 2 * sg.y + 2);
      float4 o;
      o.x = fmaf(e0.x - a0.x, tt.x, a0.x);
      o.y = fmaf(e0.y - a0.y, tt.x, a0.y);
      o.z = fmaf(e1.x - a1.x, tt.y, a1.x);
      o.w = fmaf(e1.y - a1.y, tt.y, a1.y);
      dst[off] = o;
    }
  }
}

// ---------------- generic fallback (previous verified kernel + bstart) -------
__global__ __launch_bounds__(256) void lerp_generic(
    const int* __restrict__ index, const float* __restrict__ value,
    float4* __restrict__ out4, int batch, int nk, int m, int bstart) {
  __shared__ int   s_idx[32];
  __shared__ int   s_seg[64];
  __shared__ float s_t[64];
  __shared__ float s_val[BPB * 32];  // supports nk up to 16

  const int tid = threadIdx.x;
  if (tid < nk) s_idx[tid] = index[tid];
  __syncthreads();
  if (tid < m) {
    const int p = s_idx[0] + tid + 1;
    int cnt = 0;
#pragma unroll 13
    for (int k = 0; k < nk; ++k) cnt += (s_idx[k] < p) ? 1 : 0;
    const int seg = cnt - 1;
    s_seg[tid] = seg;
    s_t[tid] = (float)(p - s_idx[seg]) / (float)(s_idx[seg + 1] - s_idx[seg]);
  }

  const int b0 = (bstart + blockIdx.x) * BPB;
  const int nb = min(BPB, batch - b0);
  const int nfl = nb * nk * 2;
  const int nf4 = nfl >> 2;
  const float4* src4 = (const float4*)(value + (long long)b0 * nk * 2);
  float4* s_val4 = (float4*)s_val;
  for (int i = tid; i < nf4; i += 256) s_val4[i] = src4[i];
  if (tid < (nfl & 3)) {
    s_val[(nf4 << 2) + tid] = value[(long long)b0 * nk * 2 + (nf4 << 2) + tid];
  }
  __syncthreads();

  const int half = m >> 1;
  const int npairs = nb * half;
  const long long outBase = (long long)b0 * half;
  const int row = nk * 2;
  for (int off = tid; off < npairs; off += 256) {
    const int bl = off / half;
    const int jp = off - bl * half;
    const float* vb = &s_val[bl * row];
    const int j0 = jp * 2;
    const int sa = s_seg[j0], sb = s_seg[j0 + 1];
    const float ta = s_t[j0], tb = s_t[j0 + 1];
    const float2 a0 = *(const float2*)&vb[2 * sa];
    const float2 e0 = *(const float2*)&vb[2 * sa + 2];
    const float2 a1 = *(const float2*)&vb[2 * sb];
    const float2 e1 = *(const float2*)&vb[2 * sb + 2];
    float4 o;
    o.x = a0.x + (e0.x - a0.x) * ta;
    o.y = a0.y + (e0.y - a0.y) * ta;
    o.z = a1.x + (e1.x - a1.x) * tb;
    o.w = a1.y + (e1.y - a1.y) * tb;
    out4[outBase + off] = o;
  }
}

extern "C" void kernel_launch(void* const* d_in, const int* in_sizes, int n_in,
                              void* d_out, int out_size, void* d_ws,
                              size_t ws_size, hipStream_t stream) {
  const int*   index = (const int*)d_in[0];
  const float* value = (const float*)d_in[1];
  float*       out   = (float*)d_out;

  const int nk    = in_sizes[0];             // 13
  const int batch = in_sizes[1] / (nk * 2);  // 262144
  const int m     = out_size / (batch * 2);  // 48

  const bool fast = (nk == 13) && (m == 48);
  if (fast) {
    const int fullBlocks = batch / BPB;  // 4096; batch % BPB == 0 here
    if (fullBlocks > 0) {
      lerp_fast<13, 48><<<fullBlocks, 256, 0, stream>>>(index, value,
                                                        (float4*)out);
    }
    const int rem = batch - fullBlocks * BPB;
    if (rem > 0) {  // tail batches via generic kernel (never for 262144)
      lerp_generic<<<1, 256, 0, stream>>>(index, value, (float4*)out, batch,
                                          nk, m, fullBlocks);
    }
  } else {
    const int grid = (batch + BPB - 1) / BPB;
    lerp_generic<<<grid, 256, 0, stream>>>(index, value, (float4*)out, batch,
                                           nk, m, 0);
  }
}